// Round 5
// baseline (498.837 us; speedup 1.0000x reference)
//
#include <hip/hip_runtime.h>
#include <hip/hip_bf16.h>

typedef unsigned short u16;
typedef unsigned int u32;
typedef __bf16 bf16_8 __attribute__((ext_vector_type(8)));
typedef float f32_4 __attribute__((ext_vector_type(4)));

#define IN_DIM 512
#define HID 64
#define OUT_DIM 40
#define CAP 64        // CSR slot capacity; deg~Poisson(16), P(deg>63)~0, guarded
#define CF_BLOCKS 512 // countfill partition size in k_work
#define NSLICE 8      // dst-range slices (1 per XCD)
#define NSEG 16       // segments per slice (atomic-tail spreading)
#define SCAP 7168     // entries per (slice,seg): mean 6250, +11 sigma guard

// ---- prep: zero cnt + bucket tails + transpose W1 fp32[512][64] -> W1t bf16[64][512] ----
__global__ void k_prep(const float* __restrict__ W1, u16* __restrict__ W1t,
                       int* __restrict__ cnt, int* __restrict__ tails, int n) {
    int i = blockIdx.x * 256 + threadIdx.x;
    if (i < n) cnt[i] = 0;
    if (i < NSLICE * NSEG) tails[i] = 0;
    if (i < IN_DIM * HID) {
        int k = i / HID, o = i % HID;
        __hip_bfloat16 v = __float2bfloat16(W1[i]);
        W1t[o * IN_DIM + k] = *reinterpret_cast<u16*>(&v);
    }
}

// ---- bucket pass: partition edges into 8 dst-range slices (x16 segments) ----
// R2-R4 byte accounting: k_work WRITE ~= 800k x 64B = one dirty sector per scattered
// 2B csr write, amplified by 8 non-coherent XCD L2s (R3 proved the mechanism). This
// pass localizes the scatter: edges are packed as (dst_local<<16 | src) u32 and
// appended (wave-ballot aggregated, ~780 atomics/counter) into per-slice buckets,
// so k_work's CF partition can drain slice s on XCD s only -> csr RFO/WB + cnt
// atomics stay in one L2. Misrouted edges (mapping heuristic) remain CORRECT.
__launch_bounds__(256)
__global__ void k_bucket(const int* __restrict__ src, const int* __restrict__ dst,
                         u32* __restrict__ bkt, int* __restrict__ tails, int N, int E) {
    const int t = threadIdx.x;
    const int lane = t & 63;
    const unsigned long long mask_lt = (lane == 0) ? 0ull : ((~0ull) >> (64 - lane));
    const int seg = (int)blockIdx.x & (NSEG - 1);
    const int stride = 256 * 256;
    for (int e = (int)blockIdx.x * 256 + t; ; e += stride) {
        bool valid = e < E;
        if (!__any(valid)) break;
        int d = 0, s = 0, b = 0;
        u32 entry = 0;
        if (valid) {
            d = dst[e];
            s = src[e];
            b = (int)((u32)(d * 8) / (u32)N);
            int lo_b = (b * N + 7) >> 3;
            entry = ((u32)(d - lo_b) << 16) | (u32)s;
        }
        #pragma unroll
        for (int bb = 0; bb < NSLICE; bb++) {
            unsigned long long m = __ballot(valid && (b == bb));
            if (!m) continue;
            int cnt_m = __popcll(m);
            int leader = __ffsll((unsigned long long)m) - 1;
            int base = 0;
            if (lane == leader) base = atomicAdd(&tails[bb * NSEG + seg], cnt_m);
            base = __shfl(base, leader);
            if (valid && b == bb) {
                int rank = __popcll(m & mask_lt);
                int idx = base + rank;
                if (idx < SCAP)
                    bkt[(size_t)(bb * NSEG + seg) * SCAP + idx] = entry;
            }
        }
    }
}

// ---- fused work: blocks [0,NT) = GEMM tiles; blocks [NT, NT+CF_BLOCKS) = count+fill ----
// R1: LDS double-buffer + register prefetch IS the pipeline scaffold; keep.
// R4: BK=64 (halved barriers) was neutral-to-worse; barrier count is not the pole ->
// reverted to the proven BK=32 body. Bank conflicts (600k) verified off critical path.
// CF partition now drains the pre-bucketed slice (blockIdx&7 -> XCD heuristic):
// coalesced bucket reads, L2-local cnt atomics + csr writes.
__launch_bounds__(256)
__global__ void k_work(const float* __restrict__ X, const u16* __restrict__ W1t,
                       const u32* __restrict__ bkt, const int* __restrict__ tails,
                       int* cnt, u16* __restrict__ csr, u16* __restrict__ hs,
                       int N, int E, int NT) {
    __shared__ __align__(16) u16 As[2][64 * 40];
    const int t = threadIdx.x;

    if ((int)blockIdx.x >= NT) {
        // ---------------- countfill partition (bucket-drain, XCD-local) ----------------
        const int slice = (int)blockIdx.x & 7;            // XCD id under round-robin
        const int rank  = ((int)blockIdx.x - NT) >> 3;    // 0..63 within slice
        const int lo_b  = (slice * N + 7) >> 3;
        #pragma unroll 1
        for (int sg = 0; sg < NSEG; sg++) {
            int ce = tails[slice * NSEG + sg];
            if (ce > SCAP) ce = SCAP;
            const u32* bp = bkt + (size_t)(slice * NSEG + sg) * SCAP;
            for (int i = rank * 256 + t; i < ce; i += 64 * 256) {
                u32 en = bp[i];
                int d = lo_b + (int)(en >> 16);
                int p = atomicAdd(&cnt[d], 1);
                if (p < CAP) csr[(size_t)d * CAP + p] = (u16)(en & 0xffffu);
            }
        }
        return;
    }

    // ---------------- GEMM tile: hs(bf16) = X @ W1 (unscaled) ----------------
    const int wave = t >> 6;
    const int lane = t & 63;
    const int m = lane & 15;
    const int quad = lane >> 4;
    const int n0 = blockIdx.x * 64;

    f32_4 acc[4];
    #pragma unroll
    for (int c = 0; c < 4; c++) acc[c] = (f32_4){0.f, 0.f, 0.f, 0.f};

    const int r_st = t >> 2;        // 0..63
    const int k_st = (t & 3) * 8;   // 0,8,16,24

    int row = n0 + r_st; if (row >= N) row = N - 1;
    const float* xp = X + (size_t)row * IN_DIM + k_st;

    f32_4 x0 = *reinterpret_cast<const f32_4*>(xp);
    f32_4 x1 = *reinterpret_cast<const f32_4*>(xp + 4);

    int buf = 0;
    for (int k0 = 0; k0 < IN_DIM; k0 += 32) {
        u16 xb[8];
        #pragma unroll
        for (int q = 0; q < 4; q++) {
            __hip_bfloat16 c0 = __float2bfloat16(x0[q]);
            __hip_bfloat16 c1 = __float2bfloat16(x1[q]);
            xb[q]     = *reinterpret_cast<u16*>(&c0);
            xb[4 + q] = *reinterpret_cast<u16*>(&c1);
        }
        *reinterpret_cast<uint4*>(&As[buf][r_st * 40 + k_st]) = *reinterpret_cast<uint4*>(xb);
        __syncthreads();

        if (k0 + 32 < IN_DIM) {
            x0 = *reinterpret_cast<const f32_4*>(xp + k0 + 32);
            x1 = *reinterpret_cast<const f32_4*>(xp + k0 + 36);
        }

        bf16_8 a = *reinterpret_cast<const bf16_8*>(&As[buf][(wave * 16 + m) * 40 + quad * 8]);
        #pragma unroll
        for (int c = 0; c < 4; c++) {    // B fragment from global W1t (64 KB, L2-hot)
            bf16_8 b = *reinterpret_cast<const bf16_8*>(
                W1t + (size_t)(c * 16 + m) * IN_DIM + k0 + quad * 8);
            acc[c] = __builtin_amdgcn_mfma_f32_16x16x32_bf16(a, b, acc[c], 0, 0, 0);
        }
        buf ^= 1;
    }

    // C layout: col = lane&15 (=m), row = quad*4 + reg. Store UNSCALED.
    const int nbase = n0 + wave * 16 + quad * 4;
    #pragma unroll
    for (int r = 0; r < 4; r++) {
        int n = nbase + r;
        if (n < N) {
            #pragma unroll
            for (int c = 0; c < 4; c++) {
                __hip_bfloat16 hv = __float2bfloat16(acc[c][r]);
                hs[(size_t)n * HID + c * 16 + m] = *reinterpret_cast<u16*>(&hv);
            }
        }
    }
}

// ---- scale pass: hs[n] = bf16(dinv[n] * hs[n]) in place (cnt is final now) ----
__global__ void k_scale(u16* __restrict__ hs, const int* __restrict__ cnt, int N) {
    int i = blockIdx.x * 256 + threadIdx.x;
    int node = i >> 3;
    if (node >= N) return;
    float dv = rsqrtf((float)cnt[node] + 1.0f);
    uint4 v = *reinterpret_cast<uint4*>(hs + (size_t)i * 8);
    uint vv[4] = {v.x, v.y, v.z, v.w};
    u16 o[8];
    #pragma unroll
    for (int q = 0; q < 4; q++) {
        float lo = __uint_as_float(vv[q] << 16) * dv;
        float hi = __uint_as_float(vv[q] & 0xFFFF0000u) * dv;
        __hip_bfloat16 bl_ = __float2bfloat16(lo);
        __hip_bfloat16 bh_ = __float2bfloat16(hi);
        o[2 * q]     = *reinterpret_cast<u16*>(&bl_);
        o[2 * q + 1] = *reinterpret_cast<u16*>(&bh_);
    }
    *reinterpret_cast<uint4*>(hs + (size_t)i * 8) = *reinterpret_cast<uint4*>(o);
}

// ---- fused agg + ReLU + FC(MFMA) ----
// hs rows are PRE-SCALED by dinv[s]; only the outer dinv[n] remains.
// CSR row loaded cooperatively (uint2 per lane), redistributed via __shfl;
// masked 16-deep gather rounds (R3: neutral vs 8-deep — gather latency not the pole).
__device__ __forceinline__ void acc_add(f32_4& a, uint2 v) {
    a[0] += __uint_as_float(v.x << 16);
    a[1] += __uint_as_float(v.x & 0xFFFF0000u);
    a[2] += __uint_as_float(v.y << 16);
    a[3] += __uint_as_float(v.y & 0xFFFF0000u);
}

#define SHP 72   // padded row pitch (bf16 elems): 144 B, conflict-free for b128 reads

__launch_bounds__(256)
__global__ void k_aggfc(const u16* __restrict__ hs, const u16* __restrict__ csr,
                        const int* __restrict__ cnt, const float* __restrict__ b1,
                        const float* __restrict__ Wfc, const float* __restrict__ bfc,
                        float* __restrict__ out, int N) {
    __shared__ __align__(16) u16 shb[16 * SHP];   // h2 rows, bf16, A-operand layout
    __shared__ __align__(16) u16 wfb[48 * SHP];   // Wfc^T padded: [o][k], rows 40..47 = 0
    __shared__ float bl[48];
    const int t = threadIdx.x;

    for (int i = t; i < 48 * HID; i += 256) {
        int o = i / HID, k = i % HID;
        float v = (o < OUT_DIM) ? Wfc[o * HID + k] : 0.f;
        __hip_bfloat16 b = __float2bfloat16(v);
        wfb[o * SHP + k] = *reinterpret_cast<u16*>(&b);
    }
    if (t < 48) bl[t] = (t < OUT_DIM) ? bfc[t] : 0.f;

    const int g = t >> 4, l = t & 15;
    const int n = blockIdx.x * 16 + g;

    if (n < N) {
        const uint2* hs2 = reinterpret_cast<const uint2*>(hs);
        f32_4 aa[4];
        #pragma unroll
        for (int q = 0; q < 4; q++) aa[q] = (f32_4){0.f, 0.f, 0.f, 0.f};
        const float dvn = rsqrtf((float)cnt[n] + 1.0f);
        acc_add(aa[0], hs2[(size_t)n * 16 + l]);         // self loop (pre-scaled)
        int deg = cnt[n]; if (deg > CAP) deg = CAP;
        // lane l holds CSR entries 4l..4l+3 of this node's row
        uint2 cv = reinterpret_cast<const uint2*>(csr + (size_t)n * CAP)[l];
        const int nn1 = N - 1;
        for (int j = 0; j < deg; j += 16) {
            int base = j >> 2;
            uint wx[4], wy[4];
            #pragma unroll
            for (int q = 0; q < 4; q++) {
                wx[q] = __shfl(cv.x, base + q, 16);
                wy[q] = __shfl(cv.y, base + q, 16);
            }
            int s[16];
            #pragma unroll
            for (int q = 0; q < 4; q++) {
                s[4 * q + 0] = (int)(wx[q] & 0xffff);
                s[4 * q + 1] = (int)(wx[q] >> 16);
                s[4 * q + 2] = (int)(wy[q] & 0xffff);
                s[4 * q + 3] = (int)(wy[q] >> 16);
            }
            uint2 v[16];
            #pragma unroll
            for (int i = 0; i < 16; i++) {
                int si = s[i] < nn1 ? s[i] : nn1;        // clamp (garbage-slot safety)
                v[i] = hs2[(size_t)si * 16 + l];
            }
            #pragma unroll
            for (int i = 0; i < 16; i++) {
                if (j + i >= deg) { v[i].x = 0u; v[i].y = 0u; }
                acc_add(aa[i & 3], v[i]);
            }
        }
        f32_4 acc = (aa[0] + aa[1]) + (aa[2] + aa[3]);
        u16 rb[4];
        #pragma unroll
        for (int q = 0; q < 4; q++) {
            float x = dvn * acc[q] + b1[l * 4 + q];
            x = x > 0.f ? x : 0.f;                       // ReLU
            __hip_bfloat16 hb = __float2bfloat16(x);
            rb[q] = *reinterpret_cast<u16*>(&hb);
        }
        *reinterpret_cast<uint2*>(&shb[g * SHP + l * 4]) = *reinterpret_cast<uint2*>(rb);
    }
    __syncthreads();

    // FC via MFMA: wave w handles o-tile w (w<3)
    const int wave = t >> 6;
    const int lane = t & 63;
    const int m = lane & 15;
    const int quad = lane >> 4;
    if (wave < 3) {
        bf16_8 a0 = *reinterpret_cast<const bf16_8*>(&shb[m * SHP + quad * 8]);
        bf16_8 a1 = *reinterpret_cast<const bf16_8*>(&shb[m * SHP + 32 + quad * 8]);
        bf16_8 b0 = *reinterpret_cast<const bf16_8*>(&wfb[(wave * 16 + m) * SHP + quad * 8]);
        bf16_8 b1 = *reinterpret_cast<const bf16_8*>(&wfb[(wave * 16 + m) * SHP + 32 + quad * 8]);
        f32_4 c = (f32_4){0.f, 0.f, 0.f, 0.f};
        c = __builtin_amdgcn_mfma_f32_16x16x32_bf16(a0, b0, c, 0, 0, 0);
        c = __builtin_amdgcn_mfma_f32_16x16x32_bf16(a1, b1, c, 0, 0, 0);
        const int o = wave * 16 + m;
        if (o < OUT_DIM) {
            const int base = blockIdx.x * 16;
            #pragma unroll
            for (int r = 0; r < 4; r++) {
                int node = base + quad * 4 + r;
                if (node < N) out[(size_t)node * OUT_DIM + o] = c[r] + bl[o];
            }
        }
    }
}

// ---------------- launch ----------------

extern "C" void kernel_launch(void* const* d_in, const int* in_sizes, int n_in,
                              void* d_out, int out_size, void* d_ws, size_t ws_size,
                              hipStream_t stream) {
    const float* X   = (const float*)d_in[0];
    const int* edges = (const int*)d_in[1];
    const float* W1  = (const float*)d_in[2];
    const float* b1  = (const float*)d_in[3];
    const float* Wfc = (const float*)d_in[4];
    const float* bfc = (const float*)d_in[5];

    const int N = in_sizes[0] / IN_DIM;
    const int E = in_sizes[1] / 2;
    const int* src = edges;
    const int* dst = edges + E;

    char* p = (char*)d_ws;
    auto carve = [&](size_t bytes) -> char* {
        char* r = p;
        p += (bytes + 255) & ~(size_t)255;
        return r;
    };
    u16* W1t   = (u16*)carve((size_t)IN_DIM * HID * 2);
    u16* hs    = (u16*)carve((size_t)N * HID * 2);
    int* cnt   = (int*)carve((size_t)N * 4);
    u16* csr   = (u16*)carve((size_t)N * CAP * 2);
    int* tails = (int*)carve((size_t)NSLICE * NSEG * 4);
    u32* bkt   = (u32*)carve((size_t)NSLICE * NSEG * SCAP * 4);

    const int nb = (N + 255) / 256;
    const int NT = (N + 63) / 64;

    k_prep  <<<nb, 256, 0, stream>>>(W1, W1t, cnt, tails, N);
    k_bucket<<<256, 256, 0, stream>>>(src, dst, bkt, tails, N, E);
    k_work  <<<NT + CF_BLOCKS, 256, 0, stream>>>(X, W1t, bkt, tails, cnt, csr, hs, N, E, NT);
    k_scale <<<(N * 8 + 255) / 256, 256, 0, stream>>>(hs, cnt, N);
    k_aggfc <<<(N + 15) / 16, 256, 0, stream>>>(hs, csr, cnt, b1, Wfc, bfc,
                                                (float*)d_out, N);
}

// Round 6
// 241.290 us; speedup vs baseline: 2.0674x; 2.0674x over previous
//
#include <hip/hip_runtime.h>
#include <hip/hip_bf16.h>

typedef unsigned short u16;
typedef __bf16 bf16_8 __attribute__((ext_vector_type(8)));
typedef float f32_4 __attribute__((ext_vector_type(4)));

#define IN_DIM 512
#define HID 64
#define OUT_DIM 40
#define CAP 64         // CSR slot capacity; deg~Poisson(16), P(deg>63)~0, guarded
#define CF_BLOCKS 1024 // countfill partition size in k_work (no-LDS kernel: all co-resident)

// ---- prep: zero cnt + transpose W1 fp32[512][64] -> W1t bf16[64][512] ----
__global__ void k_prep(const float* __restrict__ W1, u16* __restrict__ W1t,
                       int* __restrict__ cnt, int n) {
    int i = blockIdx.x * 256 + threadIdx.x;
    if (i < n) cnt[i] = 0;
    if (i < IN_DIM * HID) {
        int k = i / HID, o = i % HID;
        __hip_bfloat16 v = __float2bfloat16(W1[i]);
        W1t[o * IN_DIM + k] = *reinterpret_cast<u16*>(&v);
    }
}

// ---- fused work: blocks [0,NT) = GEMM tiles; blocks [NT, NT+CF_BLOCKS) = count+fill ----
// Ladder of falsified theories (journal):
//  R1: direct-fragment loads with distance-0 prefetch -> 117us (compiler JIT-issues loads).
//  R2: LDS-staged + dist-1 reg prefetch + barriers -> 80us (barrier vmcnt(0) drain caps it).
//  R4: BK=64 (half the barriers, 2x bytes/drain) -> neutral; barrier COUNT not the pole.
//  R5: pre-bucketing pass -> k_bucket itself 268us (ballot+leader-atomic serial chain). Revert.
// R6: direct-fragment loads (A-frag row=wave*16+m, k=quad*8 is 8 contiguous fp32 of X —
// same coalescing as staged pattern) + EXPLICIT distance-2 register pipeline (named xa/xb,
// manual 2x unroll, static indices) and NO LDS / NO barriers: waves fully decoupled, no
// drain, whole grid co-resident (zero LDS).
__launch_bounds__(256)
__global__ void k_work(const float* __restrict__ X, const u16* __restrict__ W1t,
                       const int* __restrict__ src, const int* __restrict__ dst,
                       int* cnt, u16* __restrict__ csr, u16* __restrict__ hs,
                       int N, int E, int NT) {
    const int t = threadIdx.x;

    if ((int)blockIdx.x >= NT) {
        // ---------------- countfill partition ----------------
        int tid = ((int)blockIdx.x - NT) * 256 + t;
        const int stride = CF_BLOCKS * 256;
        int e = tid;
        for (; e + stride < E; e += 2 * stride) {
            int d0 = dst[e], d1 = dst[e + stride];
            int s0 = src[e], s1 = src[e + stride];
            int p0 = atomicAdd(&cnt[d0], 1);
            int p1 = atomicAdd(&cnt[d1], 1);
            if (p0 < CAP) csr[(size_t)d0 * CAP + p0] = (u16)s0;
            if (p1 < CAP) csr[(size_t)d1 * CAP + p1] = (u16)s1;
        }
        for (; e < E; e += stride) {
            int d = dst[e];
            int p = atomicAdd(&cnt[d], 1);
            if (p < CAP) csr[(size_t)d * CAP + p] = (u16)src[e];
        }
        return;
    }

    // ---------------- GEMM tile: hs(bf16) = X @ W1 (unscaled) ----------------
    const int wave = t >> 6;
    const int lane = t & 63;
    const int m = lane & 15;
    const int quad = lane >> 4;
    const int n0 = blockIdx.x * 64;

    int row = n0 + wave * 16 + m; if (row >= N) row = N - 1;
    const float* xp = X + (size_t)row * IN_DIM + quad * 8;
    const u16* bp = W1t + (size_t)m * IN_DIM + quad * 8;

    f32_4 acc[4];
    #pragma unroll
    for (int c = 0; c < 4; c++) acc[c] = (f32_4){0.f, 0.f, 0.f, 0.f};

    // distance-2 register pipeline: xa holds k-step k0, xb holds k0+32;
    // while consuming xa we prefetch k0+64 into xa (consumed 2 half-steps later).
    f32_4 xa0 = *reinterpret_cast<const f32_4*>(xp);
    f32_4 xa1 = *reinterpret_cast<const f32_4*>(xp + 4);
    f32_4 xb0 = *reinterpret_cast<const f32_4*>(xp + 32);
    f32_4 xb1 = *reinterpret_cast<const f32_4*>(xp + 36);

    for (int k0 = 0; k0 < IN_DIM; k0 += 64) {
        // ---- half-step A: consume xa (k=k0), prefetch k0+64 ----
        union { bf16_8 v; u16 s[8]; } au;
        #pragma unroll
        for (int q = 0; q < 4; q++) {
            __hip_bfloat16 c0 = __float2bfloat16(xa0[q]);
            __hip_bfloat16 c1 = __float2bfloat16(xa1[q]);
            au.s[q]     = *reinterpret_cast<u16*>(&c0);
            au.s[4 + q] = *reinterpret_cast<u16*>(&c1);
        }
        {   // branch-free prefetch: wrap out-of-range to k=0 (valid addr, data unused)
            int kn = k0 + 64; if (kn >= IN_DIM) kn = 0;
            xa0 = *reinterpret_cast<const f32_4*>(xp + kn);
            xa1 = *reinterpret_cast<const f32_4*>(xp + kn + 4);
        }
        #pragma unroll
        for (int c = 0; c < 4; c++) {   // B fragments from global W1t (64 KB, L2-hot)
            bf16_8 b = *reinterpret_cast<const bf16_8*>(bp + (size_t)c * 16 * IN_DIM + k0);
            acc[c] = __builtin_amdgcn_mfma_f32_16x16x32_bf16(au.v, b, acc[c], 0, 0, 0);
        }

        // ---- half-step B: consume xb (k=k0+32), prefetch k0+96 ----
        union { bf16_8 v; u16 s[8]; } av;
        #pragma unroll
        for (int q = 0; q < 4; q++) {
            __hip_bfloat16 c0 = __float2bfloat16(xb0[q]);
            __hip_bfloat16 c1 = __float2bfloat16(xb1[q]);
            av.s[q]     = *reinterpret_cast<u16*>(&c0);
            av.s[4 + q] = *reinterpret_cast<u16*>(&c1);
        }
        {
            int kn = k0 + 96; if (kn >= IN_DIM) kn = 32;
            xb0 = *reinterpret_cast<const f32_4*>(xp + kn);
            xb1 = *reinterpret_cast<const f32_4*>(xp + kn + 4);
        }
        #pragma unroll
        for (int c = 0; c < 4; c++) {
            bf16_8 b = *reinterpret_cast<const bf16_8*>(bp + (size_t)c * 16 * IN_DIM + k0 + 32);
            acc[c] = __builtin_amdgcn_mfma_f32_16x16x32_bf16(av.v, b, acc[c], 0, 0, 0);
        }
    }

    // C layout: col = lane&15 (=m), row = quad*4 + reg. Store UNSCALED.
    const int nbase = n0 + wave * 16 + quad * 4;
    #pragma unroll
    for (int r = 0; r < 4; r++) {
        int n = nbase + r;
        if (n < N) {
            #pragma unroll
            for (int c = 0; c < 4; c++) {
                __hip_bfloat16 hv = __float2bfloat16(acc[c][r]);
                hs[(size_t)n * HID + c * 16 + m] = *reinterpret_cast<u16*>(&hv);
            }
        }
    }
}

// ---- scale pass: hs[n] = bf16(dinv[n] * hs[n]) in place (cnt is final now) ----
__global__ void k_scale(u16* __restrict__ hs, const int* __restrict__ cnt, int N) {
    int i = blockIdx.x * 256 + threadIdx.x;
    int node = i >> 3;
    if (node >= N) return;
    float dv = rsqrtf((float)cnt[node] + 1.0f);
    uint4 v = *reinterpret_cast<uint4*>(hs + (size_t)i * 8);
    uint vv[4] = {v.x, v.y, v.z, v.w};
    u16 o[8];
    #pragma unroll
    for (int q = 0; q < 4; q++) {
        float lo = __uint_as_float(vv[q] << 16) * dv;
        float hi = __uint_as_float(vv[q] & 0xFFFF0000u) * dv;
        __hip_bfloat16 bl_ = __float2bfloat16(lo);
        __hip_bfloat16 bh_ = __float2bfloat16(hi);
        o[2 * q]     = *reinterpret_cast<u16*>(&bl_);
        o[2 * q + 1] = *reinterpret_cast<u16*>(&bh_);
    }
    *reinterpret_cast<uint4*>(hs + (size_t)i * 8) = *reinterpret_cast<uint4*>(o);
}

// ---- fused agg + ReLU + FC(MFMA) ----
// hs rows are PRE-SCALED by dinv[s]; only the outer dinv[n] remains.
// CSR row loaded cooperatively (uint2 per lane), redistributed via __shfl;
// masked 16-deep gather rounds (R3: neutral vs 8-deep — gather latency not the pole).
__device__ __forceinline__ void acc_add(f32_4& a, uint2 v) {
    a[0] += __uint_as_float(v.x << 16);
    a[1] += __uint_as_float(v.x & 0xFFFF0000u);
    a[2] += __uint_as_float(v.y << 16);
    a[3] += __uint_as_float(v.y & 0xFFFF0000u);
}

#define SHP 72   // padded row pitch (bf16 elems): 144 B, conflict-free for b128 reads

__launch_bounds__(256)
__global__ void k_aggfc(const u16* __restrict__ hs, const u16* __restrict__ csr,
                        const int* __restrict__ cnt, const float* __restrict__ b1,
                        const float* __restrict__ Wfc, const float* __restrict__ bfc,
                        float* __restrict__ out, int N) {
    __shared__ __align__(16) u16 shb[16 * SHP];   // h2 rows, bf16, A-operand layout
    __shared__ __align__(16) u16 wfb[48 * SHP];   // Wfc^T padded: [o][k], rows 40..47 = 0
    __shared__ float bl[48];
    const int t = threadIdx.x;

    for (int i = t; i < 48 * HID; i += 256) {
        int o = i / HID, k = i % HID;
        float v = (o < OUT_DIM) ? Wfc[o * HID + k] : 0.f;
        __hip_bfloat16 b = __float2bfloat16(v);
        wfb[o * SHP + k] = *reinterpret_cast<u16*>(&b);
    }
    if (t < 48) bl[t] = (t < OUT_DIM) ? bfc[t] : 0.f;

    const int g = t >> 4, l = t & 15;
    const int n = blockIdx.x * 16 + g;

    if (n < N) {
        const uint2* hs2 = reinterpret_cast<const uint2*>(hs);
        f32_4 aa[4];
        #pragma unroll
        for (int q = 0; q < 4; q++) aa[q] = (f32_4){0.f, 0.f, 0.f, 0.f};
        const float dvn = rsqrtf((float)cnt[n] + 1.0f);
        acc_add(aa[0], hs2[(size_t)n * 16 + l]);         // self loop (pre-scaled)
        int deg = cnt[n]; if (deg > CAP) deg = CAP;
        // lane l holds CSR entries 4l..4l+3 of this node's row
        uint2 cv = reinterpret_cast<const uint2*>(csr + (size_t)n * CAP)[l];
        const int nn1 = N - 1;
        for (int j = 0; j < deg; j += 16) {
            int base = j >> 2;
            uint wx[4], wy[4];
            #pragma unroll
            for (int q = 0; q < 4; q++) {
                wx[q] = __shfl(cv.x, base + q, 16);
                wy[q] = __shfl(cv.y, base + q, 16);
            }
            int s[16];
            #pragma unroll
            for (int q = 0; q < 4; q++) {
                s[4 * q + 0] = (int)(wx[q] & 0xffff);
                s[4 * q + 1] = (int)(wx[q] >> 16);
                s[4 * q + 2] = (int)(wy[q] & 0xffff);
                s[4 * q + 3] = (int)(wy[q] >> 16);
            }
            uint2 v[16];
            #pragma unroll
            for (int i = 0; i < 16; i++) {
                int si = s[i] < nn1 ? s[i] : nn1;        // clamp (garbage-slot safety)
                v[i] = hs2[(size_t)si * 16 + l];
            }
            #pragma unroll
            for (int i = 0; i < 16; i++) {
                if (j + i >= deg) { v[i].x = 0u; v[i].y = 0u; }
                acc_add(aa[i & 3], v[i]);
            }
        }
        f32_4 acc = (aa[0] + aa[1]) + (aa[2] + aa[3]);
        u16 rb[4];
        #pragma unroll
        for (int q = 0; q < 4; q++) {
            float x = dvn * acc[q] + b1[l * 4 + q];
            x = x > 0.f ? x : 0.f;                       // ReLU
            __hip_bfloat16 hb = __float2bfloat16(x);
            rb[q] = *reinterpret_cast<u16*>(&hb);
        }
        *reinterpret_cast<uint2*>(&shb[g * SHP + l * 4]) = *reinterpret_cast<uint2*>(rb);
    }
    __syncthreads();

    // FC via MFMA: wave w handles o-tile w (w<3)
    const int wave = t >> 6;
    const int lane = t & 63;
    const int m = lane & 15;
    const int quad = lane >> 4;
    if (wave < 3) {
        bf16_8 a0 = *reinterpret_cast<const bf16_8*>(&shb[m * SHP + quad * 8]);
        bf16_8 a1 = *reinterpret_cast<const bf16_8*>(&shb[m * SHP + 32 + quad * 8]);
        bf16_8 b0 = *reinterpret_cast<const bf16_8*>(&wfb[(wave * 16 + m) * SHP + quad * 8]);
        bf16_8 b1 = *reinterpret_cast<const bf16_8*>(&wfb[(wave * 16 + m) * SHP + 32 + quad * 8]);
        f32_4 c = (f32_4){0.f, 0.f, 0.f, 0.f};
        c = __builtin_amdgcn_mfma_f32_16x16x32_bf16(a0, b0, c, 0, 0, 0);
        c = __builtin_amdgcn_mfma_f32_16x16x32_bf16(a1, b1, c, 0, 0, 0);
        const int o = wave * 16 + m;
        if (o < OUT_DIM) {
            const int base = blockIdx.x * 16;
            #pragma unroll
            for (int r = 0; r < 4; r++) {
                int node = base + quad * 4 + r;
                if (node < N) out[(size_t)node * OUT_DIM + o] = c[r] + bl[o];
            }
        }
    }
}

// ---------------- launch ----------------

extern "C" void kernel_launch(void* const* d_in, const int* in_sizes, int n_in,
                              void* d_out, int out_size, void* d_ws, size_t ws_size,
                              hipStream_t stream) {
    const float* X   = (const float*)d_in[0];
    const int* edges = (const int*)d_in[1];
    const float* W1  = (const float*)d_in[2];
    const float* b1  = (const float*)d_in[3];
    const float* Wfc = (const float*)d_in[4];
    const float* bfc = (const float*)d_in[5];

    const int N = in_sizes[0] / IN_DIM;
    const int E = in_sizes[1] / 2;
    const int* src = edges;
    const int* dst = edges + E;

    char* p = (char*)d_ws;
    auto carve = [&](size_t bytes) -> char* {
        char* r = p;
        p += (bytes + 255) & ~(size_t)255;
        return r;
    };
    u16* W1t = (u16*)carve((size_t)IN_DIM * HID * 2);
    u16* hs  = (u16*)carve((size_t)N * HID * 2);
    int* cnt = (int*)carve((size_t)N * 4);
    u16* csr = (u16*)carve((size_t)N * CAP * 2);

    const int nb = (N + 255) / 256;
    const int NT = (N + 63) / 64;

    k_prep <<<nb, 256, 0, stream>>>(W1, W1t, cnt, N);
    k_work <<<NT + CF_BLOCKS, 256, 0, stream>>>(X, W1t, src, dst, cnt, csr, hs, N, E, NT);
    k_scale<<<(N * 8 + 255) / 256, 256, 0, stream>>>(hs, cnt, N);
    k_aggfc<<<(N + 15) / 16, 256, 0, stream>>>(hs, csr, cnt, b1, Wfc, bfc,
                                               (float*)d_out, N);
}